// Round 1
// baseline (1381.446 us; speedup 1.0000x reference)
//
#include <hip/hip_runtime.h>
#include <math.h>

// BiDirectionalSymplecticLayer: B=8192 rows, state=256 (q|p, F=128), 2 dirs x 4
// leapfrog steps x 2 grad evals = 16 grad_H evals. Each grad = 4 matmuls vs
// 256x256 weights + tanh. Fully fused: one block owns TR rows, state in LDS,
// weights stream from L2. Backward matmuls use W^T staged in d_ws (512 KB).

#define TR 16          // rows per block (4 waves x 4 rows)
#define DTV 0.1f

__device__ __forceinline__ float fast_tanh(float x) {
  float ax = fabsf(x);
  float e = __expf(2.0f * ax);                       // v_exp_f32 path
  float t = 1.0f - 2.0f * __builtin_amdgcn_rcpf(e + 1.0f);  // ~1 ulp rcp
  return x < 0.0f ? -t : t;                          // e=inf -> t=1 (ok)
}

// acc[r].{x,y,z,w} = sum_i A[(rbase+r)*256+i] * W[i*256 + 4*lane + c]
// A is LDS (broadcast ds_read_b128), W is global row-major (dwordx4 coalesced).
__device__ __forceinline__ void mm256(const float* A, const float* __restrict__ W,
                                      int rbase, int lane, float4 acc[4]) {
  acc[0] = acc[1] = acc[2] = acc[3] = make_float4(0.f, 0.f, 0.f, 0.f);
  const float* Ab = A + rbase * 256;
  const float* Wp = W + 4 * lane;
#pragma unroll 2
  for (int i = 0; i < 256; i += 4) {
    float4 a0 = *(const float4*)(Ab + i);
    float4 a1 = *(const float4*)(Ab + 256 + i);
    float4 a2 = *(const float4*)(Ab + 512 + i);
    float4 a3 = *(const float4*)(Ab + 768 + i);
    float4 w0 = *(const float4*)(Wp + (i    ) * 256);
    float4 w1 = *(const float4*)(Wp + (i + 1) * 256);
    float4 w2 = *(const float4*)(Wp + (i + 2) * 256);
    float4 w3 = *(const float4*)(Wp + (i + 3) * 256);
#define MMROW(rr, ar) \
    acc[rr].x += ar.x * w0.x + ar.y * w1.x + ar.z * w2.x + ar.w * w3.x; \
    acc[rr].y += ar.x * w0.y + ar.y * w1.y + ar.z * w2.y + ar.w * w3.y; \
    acc[rr].z += ar.x * w0.z + ar.y * w1.z + ar.z * w2.z + ar.w * w3.z; \
    acc[rr].w += ar.x * w0.w + ar.y * w1.w + ar.z * w2.w + ar.w * w3.w;
    MMROW(0, a0) MMROW(1, a1) MMROW(2, a2) MMROW(3, a3)
#undef MMROW
  }
}

// W1T = W1^T, W2T = W2^T into ws (each 256x256 f32). 32 blocks: 0-15 -> W1.
__global__ void __launch_bounds__(256)
transpose_weights(const float* __restrict__ W1, const float* __restrict__ W2,
                  float* __restrict__ ws) {
  __shared__ float tile[64][65];
  int blk = blockIdx.x;
  const float* in = (blk < 16) ? W1 : W2;
  float* outp = ws + ((blk < 16) ? 0 : 65536);
  int b = blk & 15;
  int tx = b & 3, ty = b >> 2;
  int lx = threadIdx.x & 63, ly = threadIdx.x >> 6;  // 64 x 4
#pragma unroll
  for (int k = 0; k < 64; k += 4)
    tile[ly + k][lx] = in[(ty * 64 + ly + k) * 256 + tx * 64 + lx];
  __syncthreads();
#pragma unroll
  for (int k = 0; k < 64; k += 4)
    outp[(tx * 64 + ly + k) * 256 + ty * 64 + lx] = tile[lx][ly + k];
}

__global__ void __launch_bounds__(256)
symplectic_main(const float* __restrict__ x,
                const float* __restrict__ W1, const float* __restrict__ b1,
                const float* __restrict__ W2, const float* __restrict__ b2,
                const float* __restrict__ Wout,
                const float* __restrict__ W1T, const float* __restrict__ W2T,
                float* __restrict__ out) {
  __shared__ __align__(16) float S[TR * 256];   // state (q|p) per row
  __shared__ __align__(16) float H1[TR * 256];  // h1, later g1
  __shared__ __align__(16) float G[TR * 256];   // g2
  const int tid = threadIdx.x;
  const int wave = tid >> 6, lane = tid & 63;
  const int rbase = wave * 4;            // 4 rows per wave
  const int b0 = blockIdx.x * TR;
  const int j0 = 4 * lane;               // this lane's 4 columns

  float4 b1v = *(const float4*)(b1 + j0);
  float4 b2v = *(const float4*)(b2 + j0);
  float4 wov = *(const float4*)(Wout + j0);

  for (int dir = 0; dir < 2; ++dir) {
    const float dt = (dir == 0) ? DTV : -DTV;
    const float hdt = 0.5f * dt;

    // init S = (q_mid | p_mid); also emit q_mid/p_mid columns once
    for (int idx = tid; idx < TR * 256; idx += 256) {
      int r = idx >> 8, j = idx & 255;
      int b = b0 + r;
      const float* xb = x + ((size_t)(b * 64 + 32) << 7);  // x[b][32][:]
      float v = (j < 128) ? xb[j] : (xb[j - 128] - xb[j - 256]);
      S[idx] = v;
      if (dir == 0) out[(size_t)b * 768 + 256 + j] = v;
    }
    __syncthreads();

    for (int step = 0; step < 4; ++step) {
      for (int half = 0; half < 2; ++half) {
        float4 acc[4];
        // h1 = tanh(S @ W1 + b1)
        mm256(S, W1, rbase, lane, acc);
#pragma unroll
        for (int r = 0; r < 4; ++r) {
          float4 h;
          h.x = fast_tanh(acc[r].x + b1v.x);
          h.y = fast_tanh(acc[r].y + b1v.y);
          h.z = fast_tanh(acc[r].z + b1v.z);
          h.w = fast_tanh(acc[r].w + b1v.w);
          *(float4*)(H1 + (rbase + r) * 256 + j0) = h;
        }
        __syncthreads();
        // h2 = tanh(h1 @ W2 + b2);  g2 = Wout * (1 - h2^2)
        mm256(H1, W2, rbase, lane, acc);
#pragma unroll
        for (int r = 0; r < 4; ++r) {
          float4 g;
          float t;
          t = fast_tanh(acc[r].x + b2v.x); g.x = wov.x * (1.0f - t * t);
          t = fast_tanh(acc[r].y + b2v.y); g.y = wov.y * (1.0f - t * t);
          t = fast_tanh(acc[r].z + b2v.z); g.z = wov.z * (1.0f - t * t);
          t = fast_tanh(acc[r].w + b2v.w); g.w = wov.w * (1.0f - t * t);
          *(float4*)(G + (rbase + r) * 256 + j0) = g;
        }
        __syncthreads();
        // g1 = (g2 @ W2^T) * (1 - h1^2)   (overwrite H1)
        mm256(G, W2T, rbase, lane, acc);
#pragma unroll
        for (int r = 0; r < 4; ++r) {
          float4 h = *(const float4*)(H1 + (rbase + r) * 256 + j0);
          h.x = acc[r].x * (1.0f - h.x * h.x);
          h.y = acc[r].y * (1.0f - h.y * h.y);
          h.z = acc[r].z * (1.0f - h.z * h.z);
          h.w = acc[r].w * (1.0f - h.w * h.w);
          *(float4*)(H1 + (rbase + r) * 256 + j0) = h;
        }
        __syncthreads();
        // ds = g1 @ W1^T;  dq = ds[128:], dp = -ds[:128]
        // half 0: p += hdt*dp, q += dt*dq.  half 1: p += hdt*dp only.
        mm256(H1, W1T, rbase, lane, acc);
#pragma unroll
        for (int r = 0; r < 4; ++r) {
          if (lane < 32) {            // owns ds[i], i<128 -> update p[i]
            float* p = S + (rbase + r) * 256 + j0 + 128;
            float4 pv = *(const float4*)p;
            pv.x -= hdt * acc[r].x;
            pv.y -= hdt * acc[r].y;
            pv.z -= hdt * acc[r].z;
            pv.w -= hdt * acc[r].w;
            *(float4*)p = pv;
          } else if (half == 0) {     // owns ds[i], i>=128 -> update q[i-128]
            float* q = S + (rbase + r) * 256 + j0 - 128;
            float4 qv = *(const float4*)q;
            qv.x += dt * acc[r].x;
            qv.y += dt * acc[r].y;
            qv.z += dt * acc[r].z;
            qv.w += dt * acc[r].w;
            *(float4*)q = qv;
          }
        }
        __syncthreads();
      }
    }

    // emit (q,p): forward -> cols 512..767, backward -> cols 0..255
    const int obase = (dir == 0) ? 512 : 0;
    for (int idx = tid; idx < TR * 256; idx += 256) {
      int r = idx >> 8, j = idx & 255;
      out[(size_t)(b0 + r) * 768 + obase + j] = S[idx];
    }
    __syncthreads();
  }
}

extern "C" void kernel_launch(void* const* d_in, const int* in_sizes, int n_in,
                              void* d_out, int out_size, void* d_ws, size_t ws_size,
                              hipStream_t stream) {
  const float* x    = (const float*)d_in[0];
  const float* W1   = (const float*)d_in[1];
  const float* b1   = (const float*)d_in[2];
  const float* W2   = (const float*)d_in[3];
  const float* b2   = (const float*)d_in[4];
  const float* Wout = (const float*)d_in[5];
  float* ws  = (float*)d_ws;   // [0:65536) = W1^T, [65536:131072) = W2^T
  float* out = (float*)d_out;

  hipLaunchKernelGGL(transpose_weights, dim3(32), dim3(256), 0, stream, W1, W2, ws);
  hipLaunchKernelGGL(symplectic_main, dim3(8192 / TR), dim3(256), 0, stream,
                     x, W1, b1, W2, b2, Wout, ws, ws + 65536, out);
}

// Round 2
// 476.073 us; speedup vs baseline: 2.9018x; 2.9018x over previous
//
#include <hip/hip_runtime.h>
#include <math.h>

// BiDirectionalSymplecticLayer via bf16 MFMA (16x16x32), fp32 state.
// B=8192 rows, state=256. Grid 256 blocks x 512 thr (8 waves), TR=32 rows/blk.
// Weights pre-packed into MFMA B-fragment order (bf16) in d_ws:
//   mat 0 = W1, 1 = W2, 2 = W2^T, 3 = W1^T; each 65536 bf16 (128 KB).
// Per half-step: L1 h1=tanh(S@W1+b1); L2 g2=Wout*(1-tanh(h1@W2+b2)^2);
//                L3 g1=(g2@W2T)*(1-h1^2)  [h1 kept in regs];
//                L4 ds=g1@W1T; p -= hdt*ds[:128]; q += dt*ds[128:] (half 0).
// S fp32 in LDS (stride 260 for bank spread); bufS = bf16 mirror of S
// (A-operand for L1, maintained incrementally); buf1/buf2 scratch activations.

#define TRB 32
#define AST 264              // bf16 row stride: 256 + 8 pad (stride%32dw==4)
#define SST 260              // fp32 S row stride (quad spread)
#define DTV 0.1f

typedef __attribute__((ext_vector_type(8))) short short8;
typedef __attribute__((ext_vector_type(4))) float float4v;

__device__ __forceinline__ unsigned short f2bf(float f) {
  union { float f; unsigned u; } v; v.f = f;
  unsigned r = v.u + 0x7fff + ((v.u >> 16) & 1);   // RNE
  return (unsigned short)(r >> 16);
}

__device__ __forceinline__ float fast_tanh(float x) {
  float ax = fabsf(x);
  float e = __expf(2.0f * ax);
  float t = 1.0f - 2.0f * __builtin_amdgcn_rcpf(e + 1.0f);
  return x < 0.0f ? -t : t;
}

// Pack W (256x256 f32) into B-fragment order:
// dst[((kc*16+nt)*64+lane)*8 + j] = bf16( W[k][n] ), k=kc*32+(lane>>4)*8+j,
// n=nt*16+(lane&15); transposed mats read W[n][k].
__global__ void __launch_bounds__(64)
pack_weights(const float* __restrict__ W1, const float* __restrict__ W2,
             unsigned short* __restrict__ ws) {
  int g = blockIdx.x;           // 512 = 4 mats x 8 kc x 16 nt
  int mat = g >> 7, kc = (g >> 4) & 7, nt = g & 15;
  const float* src = (mat == 0 || mat == 3) ? W1 : W2;
  bool tr = mat >= 2;
  int lane = threadIdx.x;
  int k0 = kc * 32 + (lane >> 4) * 8;
  int n = nt * 16 + (lane & 15);
  unsigned short v[8];
#pragma unroll
  for (int j = 0; j < 8; ++j) {
    int k = k0 + j;
    v[j] = f2bf(tr ? src[n * 256 + k] : src[k * 256 + n]);
  }
  unsigned short* dst = ws + ((size_t)mat << 16) + (((kc * 16 + nt) * 64 + lane) << 3);
  *(short8*)dst = *(const short8*)v;
}

// acc[m][t] += A(16m..16m+15, :) @ Wmat(:, wave*32+16t .. +15), K=256.
__device__ __forceinline__ void mm_tiles(const unsigned short* Asrc,
                                         const unsigned short* __restrict__ wmat,
                                         int wave, int lane, float4v acc[2][2]) {
  const int quad = lane >> 4, l16 = lane & 15;
  acc[0][0] = acc[0][1] = acc[1][0] = acc[1][1] = (float4v){0.f, 0.f, 0.f, 0.f};
  const unsigned short* a0 = Asrc + l16 * AST + quad * 8;
  const unsigned short* a1 = a0 + 16 * AST;
  const int ntb = wave * 2;
#pragma unroll
  for (int kc = 0; kc < 8; ++kc) {
    short8 af0 = *(const short8*)(a0 + kc * 32);
    short8 af1 = *(const short8*)(a1 + kc * 32);
    short8 bf0 = *(const short8*)(wmat + (((kc * 16 + ntb) * 64 + lane) << 3));
    short8 bf1 = *(const short8*)(wmat + (((kc * 16 + ntb + 1) * 64 + lane) << 3));
    acc[0][0] = __builtin_amdgcn_mfma_f32_16x16x32_bf16(af0, bf0, acc[0][0], 0, 0, 0);
    acc[0][1] = __builtin_amdgcn_mfma_f32_16x16x32_bf16(af0, bf1, acc[0][1], 0, 0, 0);
    acc[1][0] = __builtin_amdgcn_mfma_f32_16x16x32_bf16(af1, bf0, acc[1][0], 0, 0, 0);
    acc[1][1] = __builtin_amdgcn_mfma_f32_16x16x32_bf16(af1, bf1, acc[1][1], 0, 0, 0);
  }
}

__global__ void __launch_bounds__(512)
symplectic_mfma(const float* __restrict__ x,
                const float* __restrict__ b1, const float* __restrict__ b2,
                const float* __restrict__ Wout,
                const unsigned short* __restrict__ wpack,
                float* __restrict__ out) {
  __shared__ float S[TRB * SST];
  __shared__ __align__(16) unsigned short bufS[TRB * AST];
  __shared__ __align__(16) unsigned short buf1[TRB * AST];
  __shared__ __align__(16) unsigned short buf2[TRB * AST];

  const int tid = threadIdx.x;
  const int wave = tid >> 6, lane = tid & 63;
  const int quad = lane >> 4, l16 = lane & 15;
  const int b0 = blockIdx.x * TRB;
  const int col0 = wave * 32 + l16;        // tile t adds +16

  const float b1v[2] = {b1[col0], b1[col0 + 16]};
  const float b2v[2] = {b2[col0], b2[col0 + 16]};
  const float wov[2] = {Wout[col0], Wout[col0 + 16]};

  for (int dir = 0; dir < 2; ++dir) {
    const float dt = dir ? -DTV : DTV;
    const float hdt = 0.5f * dt;

    // init S = (q_mid | p_mid), bufS = bf16(S); emit mid cols once
    for (int idx = tid; idx < TRB * 256; idx += 512) {
      int r = idx >> 8, j = idx & 255;
      int b = b0 + r;
      const float* xb = x + ((size_t)(b * 64 + 32) << 7);
      float v = (j < 128) ? xb[j] : (xb[j - 128] - xb[j - 256]);
      S[r * SST + j] = v;
      bufS[r * AST + j] = f2bf(v);
      if (dir == 0) out[(size_t)b * 768 + 256 + j] = v;
    }
    __syncthreads();

    for (int hs = 0; hs < 8; ++hs) {
      const int half = hs & 1;
      float4v acc[2][2];
      float h1r[2][2][4];

      // L1: h1 = tanh(S @ W1 + b1) -> buf1 (+ regs)
      mm_tiles(bufS, wpack, wave, lane, acc);
#pragma unroll
      for (int m = 0; m < 2; ++m)
#pragma unroll
        for (int t = 0; t < 2; ++t)
#pragma unroll
          for (int r = 0; r < 4; ++r) {
            int row = m * 16 + quad * 4 + r;
            float h = fast_tanh(acc[m][t][r] + b1v[t]);
            h1r[m][t][r] = h;
            buf1[row * AST + col0 + t * 16] = f2bf(h);
          }
      __syncthreads();

      // L2: g2 = Wout * (1 - tanh(h1 @ W2 + b2)^2) -> buf2
      mm_tiles(buf1, wpack + (1 << 16), wave, lane, acc);
#pragma unroll
      for (int m = 0; m < 2; ++m)
#pragma unroll
        for (int t = 0; t < 2; ++t)
#pragma unroll
          for (int r = 0; r < 4; ++r) {
            int row = m * 16 + quad * 4 + r;
            float h2 = fast_tanh(acc[m][t][r] + b2v[t]);
            buf2[row * AST + col0 + t * 16] = f2bf(wov[t] * (1.0f - h2 * h2));
          }
      __syncthreads();

      // L3: g1 = (g2 @ W2^T) * (1 - h1^2) -> buf1
      mm_tiles(buf2, wpack + (2 << 16), wave, lane, acc);
#pragma unroll
      for (int m = 0; m < 2; ++m)
#pragma unroll
        for (int t = 0; t < 2; ++t)
#pragma unroll
          for (int r = 0; r < 4; ++r) {
            int row = m * 16 + quad * 4 + r;
            float h = h1r[m][t][r];
            buf1[row * AST + col0 + t * 16] = f2bf(acc[m][t][r] * (1.0f - h * h));
          }
      __syncthreads();

      // L4: ds = g1 @ W1^T; leapfrog update of S (+ bf16 mirror in bufS)
      mm_tiles(buf1, wpack + (3 << 16), wave, lane, acc);
      if (wave < 4) {                       // ds cols < 128 -> p -= hdt*ds
#pragma unroll
        for (int m = 0; m < 2; ++m)
#pragma unroll
          for (int t = 0; t < 2; ++t) {
            int tc = col0 + t * 16 + 128;
#pragma unroll
            for (int r = 0; r < 4; ++r) {
              int row = m * 16 + quad * 4 + r;
              float nv = S[row * SST + tc] - hdt * acc[m][t][r];
              S[row * SST + tc] = nv;
              bufS[row * AST + tc] = f2bf(nv);
            }
          }
      } else if (half == 0) {               // ds cols >= 128 -> q += dt*ds
#pragma unroll
        for (int m = 0; m < 2; ++m)
#pragma unroll
          for (int t = 0; t < 2; ++t) {
            int tc = col0 + t * 16 - 128;
#pragma unroll
            for (int r = 0; r < 4; ++r) {
              int row = m * 16 + quad * 4 + r;
              float nv = S[row * SST + tc] + dt * acc[m][t][r];
              S[row * SST + tc] = nv;
              bufS[row * AST + tc] = f2bf(nv);
            }
          }
      }
      __syncthreads();
    }

    const int obase = dir ? 0 : 512;        // fwd -> 512..767, bwd -> 0..255
    for (int idx = tid; idx < TRB * 256; idx += 512) {
      int r = idx >> 8, j = idx & 255;
      out[(size_t)(b0 + r) * 768 + obase + j] = S[r * SST + j];
    }
    __syncthreads();                        // before next dir re-init
  }
}

extern "C" void kernel_launch(void* const* d_in, const int* in_sizes, int n_in,
                              void* d_out, int out_size, void* d_ws, size_t ws_size,
                              hipStream_t stream) {
  const float* x    = (const float*)d_in[0];
  const float* W1   = (const float*)d_in[1];
  const float* b1   = (const float*)d_in[2];
  const float* W2   = (const float*)d_in[3];
  const float* b2   = (const float*)d_in[4];
  const float* Wout = (const float*)d_in[5];
  unsigned short* wpack = (unsigned short*)d_ws;   // 4 x 65536 bf16 = 512 KB
  float* out = (float*)d_out;

  hipLaunchKernelGGL(pack_weights, dim3(512), dim3(64), 0, stream, W1, W2, wpack);
  hipLaunchKernelGGL(symplectic_mfma, dim3(8192 / TRB), dim3(512), 0, stream,
                     x, b1, b2, Wout, wpack, out);
}